// Round 7
// baseline (306.913 us; speedup 1.0000x reference)
//
#include <hip/hip_runtime.h>

namespace {

constexpr int N  = 100000;
constexpr int KD = 500;
constexpr int E  = 1200000;
constexpr int NC = 47;

constexpr int M2  = 2 * N;          // virtual nodes (graph1 | graph2)
constexpr int E2  = 2 * E;          // total edges
constexpr int NB  = 391;            // buckets of 512 virtual nodes (391*512 = 200192 >= M2)
constexpr int AB  = 586;            // scatter blocks (586*4096 >= E2)
constexpr int EBMAX = 8192;         // per-bucket edge cap (avg 6144, +26 sigma)

typedef __attribute__((ext_vector_type(8))) short short8;   // 8 bf16 = 4 VGPR
typedef __attribute__((ext_vector_type(4))) float f32x4;

__device__ __forceinline__ ushort f2bf(float f) {
    union { float f; uint u; } c; c.f = f;
    uint u = c.u + 0x7fffu + ((c.u >> 16) & 1);   // RNE
    return (ushort)(u >> 16);
}
__device__ __forceinline__ float bflo(uint v) { union { uint u; float f; } c; c.u = v << 16;        return c.f; }
__device__ __forceinline__ float bfhi(uint v) { union { uint u; float f; } c; c.u = v & 0xffff0000u; return c.f; }

// ---------------- fused prep: init fixed-capacity bucket cursors + all weight fold/transpose/bf16 ----------------

__global__ __launch_bounds__(256) void prep_all(const float* __restrict__ We, const float* __restrict__ W0,
                                                const float* __restrict__ W1, const float* __restrict__ Wc,
                                                const float* __restrict__ bc,
                                                int* __restrict__ cursor, ushort* __restrict__ wtE,
                                                ushort* __restrict__ wf0, ushort* __restrict__ wf1,
                                                ushort* __restrict__ wct, float* __restrict__ bcp) {
    int i = blockIdx.x * 256 + threadIdx.x;
    if (i < NB) cursor[i] = i * EBMAX;   // fixed-capacity bucket bases (no count/scan pass)
    if (i < 64 * 512) {
        int c = i >> 9, k = i & 511;
        wtE[i] = f2bf(k < KD ? We[k * 64 + c] : 0.f);
    }
    if (i < 64 * 192) {
        int c = i / 192, k = i % 192;
        float v0, v1;
        if (k < 64)       { v0 = W0[k * 64 + c] + W0[(128 + k) * 64 + c];
                            v1 = W1[k * 64 + c] + W1[(128 + k) * 64 + c]; }
        else if (k < 128) { v0 = W0[k * 64 + c]; v1 = W1[k * 64 + c]; }
        else              { v0 = W0[(k + 64) * 64 + c]; v1 = W1[(k + 64) * 64 + c]; }
        wf0[i] = f2bf(v0);
        wf1[i] = f2bf(v1);
        wct[i] = f2bf(c < NC ? Wc[k * NC + c] : 0.f);
    }
    if (i < 64) bcp[i] = (i < NC) ? bc[i] : 0.f;
}

// ---------------- MFMA GEMM core ----------------

__device__ __forceinline__ void stageB(const ushort* __restrict__ Wt, int ldw, int k0, short* Bs) {
    const int tid = threadIdx.x;
    #pragma unroll
    for (int i = 0; i < 2; ++i) {
        int idx = tid + i * 256;
        int c = idx >> 3, qc = (idx & 7) * 8;
        uint4 v = *reinterpret_cast<const uint4*>(Wt + (size_t)c * ldw + k0 + qc);
        *reinterpret_cast<uint4*>(Bs + (((c << 6) + qc) ^ ((c & 7) << 3))) = v;
    }
}

__device__ __forceinline__ void mma64(const short* As, const short* Bs, f32x4 acc[2][4]) {
    const int lane = threadIdx.x & 63;
    const int wrow = (threadIdx.x >> 6) * 32;
    const int llo = lane & 15, lhi = lane >> 4;
    #pragma unroll
    for (int kf = 0; kf < 2; ++kf) {
        const int kb = kf * 32 + lhi * 8;
        short8 a[2], b[4];
        #pragma unroll
        for (int m = 0; m < 2; ++m) {
            int r = wrow + m * 16 + llo;
            a[m] = *reinterpret_cast<const short8*>(As + (((r << 6) + kb) ^ ((r & 7) << 3)));
        }
        #pragma unroll
        for (int n = 0; n < 4; ++n) {
            int c = n * 16 + llo;
            b[n] = *reinterpret_cast<const short8*>(Bs + (((c << 6) + kb) ^ ((c & 7) << 3)));
        }
        #pragma unroll
        for (int m = 0; m < 2; ++m)
            #pragma unroll
            for (int n = 0; n < 4; ++n)
                acc[m][n] = __builtin_amdgcn_mfma_f32_16x16x32_bf16(a[m], b[n], acc[m][n], 0, 0, 0);
    }
}

template<bool OUTF32>
__device__ __forceinline__ void epilogue(f32x4 acc[2][4], const float* __restrict__ bias,
                                         void* out, int ldo, int ocols, int relu, int rbase) {
    const int lane = threadIdx.x & 63;
    const int wrow = (threadIdx.x >> 6) * 32;
    #pragma unroll
    for (int m = 0; m < 2; ++m) {
        #pragma unroll
        for (int r = 0; r < 4; ++r) {
            int orow = rbase + wrow + m * 16 + (lane >> 4) * 4 + r;
            if (orow >= N) continue;
            #pragma unroll
            for (int n = 0; n < 4; ++n) {
                int c = n * 16 + (lane & 15);
                float v = acc[m][n][r] + bias[c];
                if (relu) v = fmaxf(v, 0.f);
                if (OUTF32) {
                    if (c < ocols) ((float*)out)[(size_t)orow * ldo + c] = v;
                } else {
                    ((ushort*)out)[(size_t)orow * ldo + c] = f2bf(v);
                }
            }
        }
    }
}

// ---------------- fused: edge bucket-scatter (blocks 0..AB-1) || embed GEMM (blocks AB..) ----------------
// LDS union is 24 KB (scatter only needs ~3 KB) -> embed keeps 6 blocks/CU, unlike round-4's 37.9 KB union.

union SMem2 {
    struct { int h[NB]; int claim[NB]; } s;                 // ~3.1 KB
    struct { short As[128 * 64]; short Bs[64 * 64]; } g;    // 24 KB
};

__global__ __launch_bounds__(256) void scatter_embed(
        const int* __restrict__ src1, const int* __restrict__ dst1,
        const int* __restrict__ src2, const int* __restrict__ dst2,
        int* __restrict__ cursor, uint* __restrict__ ebuf,
        const float* __restrict__ x, const ushort* __restrict__ WtE,
        const float* __restrict__ bias, ushort* __restrict__ out) {
    __shared__ SMem2 sm;
    const int t = threadIdx.x;
    if (blockIdx.x < AB) {
        // ---------- bucketed edge scatter ----------
        int mb[16];
        uint mu[16];
        for (int b = t; b < NB; b += 256) sm.s.h[b] = 0;
        __syncthreads();
        #pragma unroll
        for (int q = 0; q < 16; ++q) {
            int i = blockIdx.x * 4096 + q * 256 + t;
            if (i < E2) {
                int g = i >= E;
                int idx = i - g * E;
                int s = g ? src2[idx] : src1[idx];
                int d = g ? dst2[idx] : dst1[idx];
                int v = g * N + s;
                mb[q] = v >> 9;
                mu[q] = ((uint)(v & 511) << 17) | (uint)d;
                atomicAdd(&sm.s.h[mb[q]], 1);
            } else {
                mb[q] = -1;
                mu[q] = 0;
            }
        }
        __syncthreads();
        for (int b = t; b < NB; b += 256)
            sm.s.claim[b] = sm.s.h[b] ? atomicAdd(&cursor[b], sm.s.h[b]) : 0;
        __syncthreads();
        for (int b = t; b < NB; b += 256) sm.s.h[b] = 0;
        __syncthreads();
        #pragma unroll
        for (int q = 0; q < 16; ++q) {
            if (mb[q] >= 0) {
                int r = atomicAdd(&sm.s.h[mb[q]], 1);
                ebuf[sm.s.claim[mb[q]] + r] = mu[q];
            }
        }
    } else {
        // ---------- embed GEMM: r0 = relu(x @ W_embed + b) ----------
        const int rbase = (blockIdx.x - AB) * 128;
        f32x4 acc[2][4] = {};
        for (int k0 = 0; k0 < 512; k0 += 64) {
            __syncthreads();
            #pragma unroll
            for (int i = 0; i < 8; ++i) {
                int idx = t + i * 256;
                int r = idx >> 4, qc = (idx & 15) * 4;
                int grow = rbase + r;
                float4 v = {0.f, 0.f, 0.f, 0.f};
                if (grow < N && k0 + qc < KD) v = *reinterpret_cast<const float4*>(x + (size_t)grow * KD + k0 + qc);
                uint2 p;
                p.x = (uint)f2bf(v.x) | ((uint)f2bf(v.y) << 16);
                p.y = (uint)f2bf(v.z) | ((uint)f2bf(v.w) << 16);
                *reinterpret_cast<uint2*>(sm.g.As + (((r << 6) + qc) ^ ((r & 7) << 3))) = p;
            }
            stageB(WtE, 512, k0, sm.g.Bs);
            __syncthreads();
            mma64(sm.g.As, sm.g.Bs, acc);
        }
        epilogue<false>(acc, bias, out, 192, 64, 1, rbase);
    }
}

// one block per bucket: build 512-node CSR window in LDS, write rp/rpe/invd/col
__global__ __launch_bounds__(256) void csr_finalize(const uint* __restrict__ ebuf, const int* __restrict__ cursor,
                                                    int* __restrict__ rp, int* __restrict__ rpe,
                                                    float* __restrict__ invd, int* __restrict__ col) {
    __shared__ uint eb[EBMAX];
    __shared__ int h[512];
    __shared__ int ex[512];
    __shared__ int ps[256];
    int bid = blockIdx.x;
    int t = threadIdx.x;
    int b0 = bid * EBMAX;
    int cnt = cursor[bid] - b0;
    if (cnt > EBMAX) cnt = EBMAX;
    if (cnt < 0) cnt = 0;
    h[t] = 0; h[t + 256] = 0;
    for (int j = t; j < cnt; j += 256) eb[j] = ebuf[b0 + j];
    __syncthreads();
    for (int j = t; j < cnt; j += 256) atomicAdd(&h[eb[j] >> 17], 1);
    __syncthreads();
    int pv = h[2 * t] + h[2 * t + 1];
    ps[t] = pv;
    __syncthreads();
    for (int off = 1; off < 256; off <<= 1) {
        int xv = (t >= off) ? ps[t - off] : 0;
        __syncthreads();
        ps[t] += xv;
        __syncthreads();
    }
    int e2 = ps[t] - pv;
    ex[2 * t] = e2;
    ex[2 * t + 1] = e2 + h[2 * t];
    __syncthreads();
    #pragma unroll
    for (int q = 0; q < 2; ++q) {
        int k = q * 256 + t;
        int n = bid * 512 + k;
        if (n < M2) {
            int st = b0 + ex[k];
            int dv = h[k];
            rp[n]  = st;
            rpe[n] = st + dv;
            invd[n] = 1.0f / (float)(dv > 1 ? dv : 1);
        }
    }
    __syncthreads();
    for (int j = t; j < cnt; j += 256) {
        uint u = eb[j];
        int ls = u >> 17;
        int r = atomicAdd(&ex[ls], 1);
        col[b0 + r] = (int)(u & 0x1FFFFu) * 384;   // byte offset of node row in embB
    }
}

// ---------------- fused layer: SPMM gathered directly into A-tiles of the layer GEMM ----------------
// seg0 = r_prev (strided load from embB); seg1/seg2 = n1/n2 computed in-kernel (spmm7 loop verbatim,
// result written to As LDS instead of global n1b/n2b). Removes the 25.6MB x2 round-trip per layer.

__global__ __launch_bounds__(256) void gemm_layer(const ushort* __restrict__ rprev,
                                                  const ushort* __restrict__ table, int colOff,
                                                  const int* __restrict__ rp, const int* __restrict__ rpe,
                                                  const int* __restrict__ col, const float* __restrict__ invd,
                                                  const ushort* __restrict__ Wt,
                                                  const float* __restrict__ bias,
                                                  ushort* __restrict__ out) {
    __shared__ short As[128 * 64];
    __shared__ short Bs[64 * 64];
    const int tid = threadIdx.x;
    const int rbase = blockIdx.x * 128;
    f32x4 acc[2][4] = {};

    // ---- seg0: r_prev ----
    #pragma unroll
    for (int i = 0; i < 4; ++i) {
        int idx = tid + i * 256;
        int r = idx >> 3, qc = (idx & 7) * 8;
        int grow = rbase + r;
        uint4 v = {0u, 0u, 0u, 0u};
        if (grow < N) v = *reinterpret_cast<const uint4*>(rprev + (size_t)grow * 192 + qc);
        *reinterpret_cast<uint4*>(As + (((r << 6) + qc) ^ ((r & 7) << 3))) = v;
    }
    stageB(Wt, 192, 0, Bs);
    __syncthreads();
    mma64(As, Bs, acc);

    // ---- seg1 (graph1) / seg2 (graph2): gather + reduce -> As ----
    const int row = tid >> 3;        // 32 rows per sweep
    const int ls  = tid & 7;
    const char* hb = (const char*)(table + colOff) + ls * 16;
    #pragma unroll
    for (int g = 0; g < 2; ++g) {
        __syncthreads();   // previous mma64 done; As writable
        #pragma unroll
        for (int sw = 0; sw < 4; ++sw) {
            int r = sw * 32 + row;
            int grow = rbase + r;
            uint4 o = {0u, 0u, 0u, 0u};
            if (grow < N) {
                int node = grow + g * N;
                float w = invd[node];
                int s = rp[node], e = rpe[node];
                int e1 = e - 1;
                float a0=0.f,a1=0.f,a2=0.f,a3=0.f,a4=0.f,a5=0.f,a6=0.f,a7=0.f;
                for (int j = s; j < e; j += 8) {
                    int off[8];
                    float wv[8];
                    #pragma unroll
                    for (int u = 0; u < 8; ++u) {
                        int jj = j + u;
                        int cidx = jj < e ? jj : e1;
                        off[u] = col[cidx];
                        wv[u] = jj < e ? 1.f : 0.f;
                    }
                    uint4 v[8];
                    #pragma unroll
                    for (int u = 0; u < 8; ++u) v[u] = *reinterpret_cast<const uint4*>(hb + off[u]);
                    #pragma unroll
                    for (int u = 0; u < 8; ++u) {
                        a0 = fmaf(wv[u], bflo(v[u].x), a0); a1 = fmaf(wv[u], bfhi(v[u].x), a1);
                        a2 = fmaf(wv[u], bflo(v[u].y), a2); a3 = fmaf(wv[u], bfhi(v[u].y), a3);
                        a4 = fmaf(wv[u], bflo(v[u].z), a4); a5 = fmaf(wv[u], bfhi(v[u].z), a5);
                        a6 = fmaf(wv[u], bflo(v[u].w), a6); a7 = fmaf(wv[u], bfhi(v[u].w), a7);
                    }
                }
                o.x = (uint)f2bf(a0 * w) | ((uint)f2bf(a1 * w) << 16);
                o.y = (uint)f2bf(a2 * w) | ((uint)f2bf(a3 * w) << 16);
                o.z = (uint)f2bf(a4 * w) | ((uint)f2bf(a5 * w) << 16);
                o.w = (uint)f2bf(a6 * w) | ((uint)f2bf(a7 * w) << 16);
            }
            *reinterpret_cast<uint4*>(As + (((r << 6) + ls * 8) ^ ((r & 7) << 3))) = o;
        }
        stageB(Wt, 192, (1 + g) * 64, Bs);
        __syncthreads();
        mma64(As, Bs, acc);
    }
    epilogue<false>(acc, bias, out, 192, 64, 1, rbase);
}

// ---------------- classifier GEMM (3 strided embB segments, f32 out) ----------------

__global__ __launch_bounds__(256) void gemm_cls(const ushort* __restrict__ a0,
                                                const ushort* __restrict__ a1,
                                                const ushort* __restrict__ a2,
                                                const ushort* __restrict__ Wt,
                                                const float* __restrict__ bias,
                                                float* __restrict__ out) {
    __shared__ short As[128 * 64];
    __shared__ short Bs[64 * 64];
    const int tid = threadIdx.x;
    const int rbase = blockIdx.x * 128;
    f32x4 acc[2][4] = {};
    const ushort* aseg[3] = {a0, a1, a2};
    #pragma unroll
    for (int seg = 0; seg < 3; ++seg) {
        const ushort* A = aseg[seg];
        __syncthreads();
        #pragma unroll
        for (int i = 0; i < 4; ++i) {
            int idx = tid + i * 256;
            int r = idx >> 3, qc = (idx & 7) * 8;
            int grow = rbase + r;
            uint4 v = {0u, 0u, 0u, 0u};
            if (grow < N) v = *reinterpret_cast<const uint4*>(A + (size_t)grow * 192 + qc);
            *reinterpret_cast<uint4*>(As + (((r << 6) + qc) ^ ((r & 7) << 3))) = v;
        }
        stageB(Wt, 192, seg * 64, Bs);
        __syncthreads();
        mma64(As, Bs, acc);
    }
    epilogue<true>(acc, bias, out, NC, NC, 0, rbase);
}

} // namespace

extern "C" void kernel_launch(void* const* d_in, const int* in_sizes, int n_in,
                              void* d_out, int out_size, void* d_ws, size_t ws_size,
                              hipStream_t stream) {
    const float* x       = (const float*)d_in[0];
    const int*   ei1     = (const int*)d_in[1];
    const int*   ei2     = (const int*)d_in[2];
    const float* W_embed = (const float*)d_in[3];
    const float* b_embed = (const float*)d_in[4];
    const float* W0      = (const float*)d_in[5];
    const float* b0      = (const float*)d_in[6];
    const float* W1      = (const float*)d_in[7];
    const float* b1      = (const float*)d_in[8];
    const float* Wc      = (const float*)d_in[9];
    const float* bc      = (const float*)d_in[10];
    float* out = (float*)d_out;

    char* ws = (char*)d_ws;
    size_t off = 0;
    auto alloc = [&](size_t bytes) -> void* {
        void* p = ws + off;
        off += (bytes + 255) & ~(size_t)255;
        return p;
    };

    ushort* embB  = (ushort*)alloc((size_t)N * 192 * 2);  // bf16 [N][192]: r0 | r1 | r2
    int*    col   = (int*)alloc((size_t)NB * EBMAX * 4);
    uint*   ebuf  = (uint*)alloc((size_t)NB * EBMAX * 4);
    int*    rp    = (int*)alloc((size_t)M2 * 4);
    int*    rpe   = (int*)alloc((size_t)M2 * 4);
    float*  invd  = (float*)alloc((size_t)M2 * 4);
    int*    bcur  = (int*)alloc((NB + 1) * 4);
    ushort* wtE   = (ushort*)alloc(64 * 512 * 2);
    ushort* weff0 = (ushort*)alloc(64 * 192 * 2);
    ushort* weff1 = (ushort*)alloc(64 * 192 * 2);
    ushort* wct   = (ushort*)alloc(64 * 192 * 2);
    float*  bcp   = (float*)alloc(64 * 4);
    if (off > ws_size) return;

    const int* src1 = ei1, *dst1 = ei1 + E;
    const int* src2 = ei2, *dst2 = ei2 + E;

    const int GB = (N + 127) / 128;          // 782

    // ---- prep (bucket cursors to b*EBMAX + all weights) ----
    prep_all<<<128, 256, 0, stream>>>(W_embed, W0, W1, Wc, bc, bcur, wtE, weff0, weff1, wct, bcp);

    // ---- fused: edge scatter || embed GEMM ----
    scatter_embed<<<AB + GB, 256, 0, stream>>>(src1, dst1, src2, dst2, bcur, ebuf,
                                               x, wtE, b_embed, embB);

    // ---- CSR finalize ----
    csr_finalize<<<NB, 256, 0, stream>>>(ebuf, bcur, rp, rpe, invd, col);

    // ---- layers (SPMM fused into GEMM A-staging) ----
    for (int layer = 0; layer < 2; ++layer) {
        const ushort* rprev = embB + 64 * layer;
        const ushort* Wl = (layer == 0) ? weff0 : weff1;
        const float*  bl = (layer == 0) ? b0 : b1;
        gemm_layer<<<GB, 256, 0, stream>>>(rprev, embB, 64 * layer, rp, rpe, col, invd,
                                           Wl, bl, embB + 64 * (layer + 1));
    }

    // ---- classifier: logits = emb @ Wc + bc (f32 out, 47 cols) ----
    gemm_cls<<<GB, 256, 0, stream>>>(embB, embB + 64, embB + 128, wct, bcp, out);
}

// Round 8
// 223.578 us; speedup vs baseline: 1.3727x; 1.3727x over previous
//
#include <hip/hip_runtime.h>

namespace {

constexpr int N  = 100000;
constexpr int KD = 500;
constexpr int E  = 1200000;
constexpr int NC = 47;

constexpr int M2  = 2 * N;          // virtual nodes (graph1 | graph2)
constexpr int E2  = 2 * E;          // total edges
constexpr int NB  = 391;            // buckets of 512 virtual nodes (391*512 = 200192 >= M2)
constexpr int AB  = 586;            // scatter blocks (586*4096 >= E2)
constexpr int EBMAX = 8192;         // per-bucket edge cap (avg 6144, +26 sigma)

typedef __attribute__((ext_vector_type(8))) short short8;   // 8 bf16 = 4 VGPR
typedef __attribute__((ext_vector_type(4))) float f32x4;

__device__ __forceinline__ ushort f2bf(float f) {
    union { float f; uint u; } c; c.f = f;
    uint u = c.u + 0x7fffu + ((c.u >> 16) & 1);   // RNE
    return (ushort)(u >> 16);
}
__device__ __forceinline__ float bflo(uint v) { union { uint u; float f; } c; c.u = v << 16;        return c.f; }
__device__ __forceinline__ float bfhi(uint v) { union { uint u; float f; } c; c.u = v & 0xffff0000u; return c.f; }

// ---------------- fused prep: init fixed-capacity bucket cursors + all weight fold/transpose/bf16 ----------------

__global__ __launch_bounds__(256) void prep_all(const float* __restrict__ We, const float* __restrict__ W0,
                                                const float* __restrict__ W1, const float* __restrict__ Wc,
                                                const float* __restrict__ bc,
                                                int* __restrict__ cursor, ushort* __restrict__ wtE,
                                                ushort* __restrict__ wf0, ushort* __restrict__ wf1,
                                                ushort* __restrict__ wct, float* __restrict__ bcp) {
    int i = blockIdx.x * 256 + threadIdx.x;
    if (i < NB) cursor[i] = i * EBMAX;   // fixed-capacity bucket bases (no count/scan pass)
    if (i < 64 * 512) {
        int c = i >> 9, k = i & 511;
        wtE[i] = f2bf(k < KD ? We[k * 64 + c] : 0.f);
    }
    if (i < 64 * 192) {
        int c = i / 192, k = i % 192;
        float v0, v1;
        if (k < 64)       { v0 = W0[k * 64 + c] + W0[(128 + k) * 64 + c];
                            v1 = W1[k * 64 + c] + W1[(128 + k) * 64 + c]; }
        else if (k < 128) { v0 = W0[k * 64 + c]; v1 = W1[k * 64 + c]; }
        else              { v0 = W0[(k + 64) * 64 + c]; v1 = W1[(k + 64) * 64 + c]; }
        wf0[i] = f2bf(v0);
        wf1[i] = f2bf(v1);
        wct[i] = f2bf(c < NC ? Wc[k * NC + c] : 0.f);
    }
    if (i < 64) bcp[i] = (i < NC) ? bc[i] : 0.f;
}

// ---------------- bucketed edge scatter (fixed-capacity buckets, no global scan) ----------------

__global__ __launch_bounds__(256) void bucket_scatter(const int* __restrict__ src1, const int* __restrict__ dst1,
                                                      const int* __restrict__ src2, const int* __restrict__ dst2,
                                                      int* __restrict__ cursor, uint* __restrict__ ebuf) {
    __shared__ int h[NB];
    __shared__ int claim[NB];
    int t = threadIdx.x;
    int mb[16];
    uint mu[16];
    for (int b = t; b < NB; b += 256) h[b] = 0;
    __syncthreads();
    #pragma unroll
    for (int q = 0; q < 16; ++q) {
        int i = blockIdx.x * 4096 + q * 256 + t;
        if (i < E2) {
            int g = i >= E;
            int idx = i - g * E;
            int s = g ? src2[idx] : src1[idx];
            int d = g ? dst2[idx] : dst1[idx];
            int v = g * N + s;
            mb[q] = v >> 9;
            mu[q] = ((uint)(v & 511) << 17) | (uint)d;
            atomicAdd(&h[mb[q]], 1);
        } else {
            mb[q] = -1;
            mu[q] = 0;
        }
    }
    __syncthreads();
    for (int b = t; b < NB; b += 256)
        claim[b] = h[b] ? atomicAdd(&cursor[b], h[b]) : 0;
    __syncthreads();
    for (int b = t; b < NB; b += 256) h[b] = 0;
    __syncthreads();
    #pragma unroll
    for (int q = 0; q < 16; ++q) {
        if (mb[q] >= 0) {
            int r = atomicAdd(&h[mb[q]], 1);
            ebuf[claim[mb[q]] + r] = mu[q];
        }
    }
}

// one block per bucket: build 512-node CSR window in LDS, write rp/rpe/invd/col
__global__ __launch_bounds__(256) void csr_finalize(const uint* __restrict__ ebuf, const int* __restrict__ cursor,
                                                    int* __restrict__ rp, int* __restrict__ rpe,
                                                    float* __restrict__ invd, int* __restrict__ col) {
    __shared__ uint eb[EBMAX];
    __shared__ int h[512];
    __shared__ int ex[512];
    __shared__ int ps[256];
    int bid = blockIdx.x;
    int t = threadIdx.x;
    int b0 = bid * EBMAX;
    int cnt = cursor[bid] - b0;
    if (cnt > EBMAX) cnt = EBMAX;
    if (cnt < 0) cnt = 0;
    h[t] = 0; h[t + 256] = 0;
    for (int j = t; j < cnt; j += 256) eb[j] = ebuf[b0 + j];
    __syncthreads();
    for (int j = t; j < cnt; j += 256) atomicAdd(&h[eb[j] >> 17], 1);
    __syncthreads();
    int pv = h[2 * t] + h[2 * t + 1];
    ps[t] = pv;
    __syncthreads();
    for (int off = 1; off < 256; off <<= 1) {
        int xv = (t >= off) ? ps[t - off] : 0;
        __syncthreads();
        ps[t] += xv;
        __syncthreads();
    }
    int e2 = ps[t] - pv;
    ex[2 * t] = e2;
    ex[2 * t + 1] = e2 + h[2 * t];
    __syncthreads();
    #pragma unroll
    for (int q = 0; q < 2; ++q) {
        int k = q * 256 + t;
        int n = bid * 512 + k;
        if (n < M2) {
            int st = b0 + ex[k];
            int dv = h[k];
            rp[n]  = st;
            rpe[n] = st + dv;
            invd[n] = 1.0f / (float)(dv > 1 ? dv : 1);
        }
    }
    __syncthreads();
    for (int j = t; j < cnt; j += 256) {
        uint u = eb[j];
        int ls = u >> 17;
        int r = atomicAdd(&ex[ls], 1);
        col[b0 + r] = (int)(u & 0x1FFFFu) * 384;   // byte offset of node row in embB
    }
}

// ---------------- MFMA GEMM core ----------------

__device__ __forceinline__ void stageB(const ushort* __restrict__ Wt, int ldw, int k0, short* Bs) {
    const int tid = threadIdx.x;
    #pragma unroll
    for (int i = 0; i < 2; ++i) {
        int idx = tid + i * 256;
        int c = idx >> 3, qc = (idx & 7) * 8;
        uint4 v = *reinterpret_cast<const uint4*>(Wt + (size_t)c * ldw + k0 + qc);
        *reinterpret_cast<uint4*>(Bs + (((c << 6) + qc) ^ ((c & 7) << 3))) = v;
    }
}

__device__ __forceinline__ void mma64(const short* As, const short* Bs, f32x4 acc[2][4]) {
    const int lane = threadIdx.x & 63;
    const int wrow = (threadIdx.x >> 6) * 32;
    const int llo = lane & 15, lhi = lane >> 4;
    #pragma unroll
    for (int kf = 0; kf < 2; ++kf) {
        const int kb = kf * 32 + lhi * 8;
        short8 a[2], b[4];
        #pragma unroll
        for (int m = 0; m < 2; ++m) {
            int r = wrow + m * 16 + llo;
            a[m] = *reinterpret_cast<const short8*>(As + (((r << 6) + kb) ^ ((r & 7) << 3)));
        }
        #pragma unroll
        for (int n = 0; n < 4; ++n) {
            int c = n * 16 + llo;
            b[n] = *reinterpret_cast<const short8*>(Bs + (((c << 6) + kb) ^ ((c & 7) << 3)));
        }
        #pragma unroll
        for (int m = 0; m < 2; ++m)
            #pragma unroll
            for (int n = 0; n < 4; ++n)
                acc[m][n] = __builtin_amdgcn_mfma_f32_16x16x32_bf16(a[m], b[n], acc[m][n], 0, 0, 0);
    }
}

template<bool OUTF32>
__device__ __forceinline__ void epilogue(f32x4 acc[2][4], const float* __restrict__ bias,
                                         void* out, int ldo, int ocols, int relu, int rbase) {
    const int lane = threadIdx.x & 63;
    const int wrow = (threadIdx.x >> 6) * 32;
    #pragma unroll
    for (int m = 0; m < 2; ++m) {
        #pragma unroll
        for (int r = 0; r < 4; ++r) {
            int orow = rbase + wrow + m * 16 + (lane >> 4) * 4 + r;
            if (orow >= N) continue;
            #pragma unroll
            for (int n = 0; n < 4; ++n) {
                int c = n * 16 + (lane & 15);
                float v = acc[m][n][r] + bias[c];
                if (relu) v = fmaxf(v, 0.f);
                if (OUTF32) {
                    if (c < ocols) ((float*)out)[(size_t)orow * ldo + c] = v;
                } else {
                    ((ushort*)out)[(size_t)orow * ldo + c] = f2bf(v);
                }
            }
        }
    }
}

// ---------------- embed GEMM, full-row staging: 32-row blocks, each x row read once, contiguously ----------------
// As = 32 rows x 512 cols bf16 (32 KB), staged in ONE deep-MLP burst (16 independent float4/thread along a row).
// k-loop then only re-stages the L2-hot 8KB Bs. N = 3125*32 exactly -> no row guards.

__global__ __launch_bounds__(256) void gemm_embed(const float* __restrict__ x,
                                                  const ushort* __restrict__ WtE,
                                                  const float* __restrict__ bias,
                                                  ushort* __restrict__ out) {
    __shared__ short As[32 * 512];
    __shared__ short Bs[64 * 64];
    const int tid = threadIdx.x;
    const int rbase = blockIdx.x * 32;
    const int r = tid >> 3;          // 0..31
    const int j = tid & 7;
    const int swz = (r & 7) << 3;    // element-index XOR within 64-elem granule

    // ---- stage full 32x512 A-panel: thread (r,j) reads row r cols j*4 + i*32 ----
    const float* xrow = x + (size_t)(rbase + r) * KD;
    float4 pv[16];
    #pragma unroll
    for (int i = 0; i < 16; ++i) {
        int qc = i * 32 + j * 4;
        float4 v = {0.f, 0.f, 0.f, 0.f};
        if (qc < KD) v = *reinterpret_cast<const float4*>(xrow + qc);
        pv[i] = v;
    }
    #pragma unroll
    for (int i = 0; i < 16; ++i) {
        int qc = i * 32 + j * 4;
        uint2 p;
        p.x = (uint)f2bf(pv[i].x) | ((uint)f2bf(pv[i].y) << 16);
        p.y = (uint)f2bf(pv[i].z) | ((uint)f2bf(pv[i].w) << 16);
        *reinterpret_cast<uint2*>(As + ((r << 9) + (qc ^ swz))) = p;
    }

    // ---- k-loop: Bs re-stage + MFMA; wave w owns output cols w*16..w*16+15 ----
    const int lane = tid & 63;
    const int w = tid >> 6;
    const int llo = lane & 15, lhi = lane >> 4;
    f32x4 acc[2] = {};
    for (int k0 = 0; k0 < 512; k0 += 64) {
        __syncthreads();             // covers As staging (first iter) and prior mma reads of Bs
        stageB(WtE, 512, k0, Bs);
        __syncthreads();
        #pragma unroll
        for (int kf = 0; kf < 2; ++kf) {
            const int kbl = kf * 32 + lhi * 8;          // k within 64-tile
            const int kab = k0 + kbl;                   // absolute k
            short8 a[2], b;
            #pragma unroll
            for (int m = 0; m < 2; ++m) {
                int ar = m * 16 + llo;
                a[m] = *reinterpret_cast<const short8*>(As + ((ar << 9) + (kab ^ ((ar & 7) << 3))));
            }
            {
                int c = w * 16 + llo;
                b = *reinterpret_cast<const short8*>(Bs + (((c << 6) + kbl) ^ ((c & 7) << 3)));
            }
            #pragma unroll
            for (int m = 0; m < 2; ++m)
                acc[m] = __builtin_amdgcn_mfma_f32_16x16x32_bf16(a[m], b, acc[m], 0, 0, 0);
        }
    }

    // ---- epilogue: bf16 out, ld 192 ----
    #pragma unroll
    for (int m = 0; m < 2; ++m) {
        #pragma unroll
        for (int rr = 0; rr < 4; ++rr) {
            int orow = rbase + m * 16 + lhi * 4 + rr;
            int c = w * 16 + llo;
            float v = acc[m][rr] + bias[c];
            v = fmaxf(v, 0.f);
            out[(size_t)orow * 192 + c] = f2bf(v);
        }
    }
}

template<bool OUTF32>
__global__ __launch_bounds__(256) void gemm3(const ushort* __restrict__ a0, int lda0,
                                             const ushort* __restrict__ a1, int lda1,
                                             const ushort* __restrict__ a2, int lda2,
                                             const ushort* __restrict__ Wt,
                                             const float* __restrict__ bias,
                                             void* out, int ldo, int ocols, int relu) {
    __shared__ short As[128 * 64];
    __shared__ short Bs[64 * 64];
    const int tid = threadIdx.x;
    const int rbase = blockIdx.x * 128;
    f32x4 acc[2][4] = {};
    const ushort* aseg[3] = {a0, a1, a2};
    const int ldas[3] = {lda0, lda1, lda2};
    #pragma unroll
    for (int seg = 0; seg < 3; ++seg) {
        const ushort* A = aseg[seg];
        const int lda = ldas[seg];
        __syncthreads();
        #pragma unroll
        for (int i = 0; i < 4; ++i) {
            int idx = tid + i * 256;
            int r = idx >> 3, qc = (idx & 7) * 8;
            int grow = rbase + r;
            uint4 v = {0u, 0u, 0u, 0u};
            if (grow < N) v = *reinterpret_cast<const uint4*>(A + (size_t)grow * lda + qc);
            *reinterpret_cast<uint4*>(As + (((r << 6) + qc) ^ ((r & 7) << 3))) = v;
        }
        stageB(Wt, 192, seg * 64, Bs);
        __syncthreads();
        mma64(As, Bs, acc);
    }
    epilogue<OUTF32>(acc, bias, out, ldo, ocols, relu, rbase);
}

// ---------------- SPMM: 8 lanes per node, uint4 row reads (1 line per edge), 8-deep MLP unroll ----------------

__global__ __launch_bounds__(256) void spmm7(const int* __restrict__ rp, const int* __restrict__ rpe,
                                             const int* __restrict__ col,
                                             const float* __restrict__ invd,
                                             const ushort* __restrict__ table, int colOff,
                                             ushort* __restrict__ n1b, ushort* __restrict__ n2b) {
    int gid = (blockIdx.x * 256 + threadIdx.x) >> 3;   // virtual node
    int ls = threadIdx.x & 7;
    if (gid >= M2) return;
    const char* hb = (const char*)(table + colOff) + ls * 16;
    float w = invd[gid];
    int s = rp[gid], e = rpe[gid];
    int e1 = e - 1;
    float a0=0.f,a1=0.f,a2=0.f,a3=0.f,a4=0.f,a5=0.f,a6=0.f,a7=0.f;
    for (int j = s; j < e; j += 8) {
        int off[8];
        float wv[8];
        #pragma unroll
        for (int u = 0; u < 8; ++u) {
            int jj = j + u;
            int cidx = jj < e ? jj : e1;
            off[u] = col[cidx];
            wv[u] = jj < e ? 1.f : 0.f;
        }
        uint4 v[8];
        #pragma unroll
        for (int u = 0; u < 8; ++u) v[u] = *reinterpret_cast<const uint4*>(hb + off[u]);
        #pragma unroll
        for (int u = 0; u < 8; ++u) {
            a0 = fmaf(wv[u], bflo(v[u].x), a0); a1 = fmaf(wv[u], bfhi(v[u].x), a1);
            a2 = fmaf(wv[u], bflo(v[u].y), a2); a3 = fmaf(wv[u], bfhi(v[u].y), a3);
            a4 = fmaf(wv[u], bflo(v[u].z), a4); a5 = fmaf(wv[u], bfhi(v[u].z), a5);
            a6 = fmaf(wv[u], bflo(v[u].w), a6); a7 = fmaf(wv[u], bfhi(v[u].w), a7);
        }
    }
    int g = gid >= N;
    int node = gid - g * N;
    ushort* op = g ? n2b : n1b;
    uint4 o;
    o.x = (uint)f2bf(a0 * w) | ((uint)f2bf(a1 * w) << 16);
    o.y = (uint)f2bf(a2 * w) | ((uint)f2bf(a3 * w) << 16);
    o.z = (uint)f2bf(a4 * w) | ((uint)f2bf(a5 * w) << 16);
    o.w = (uint)f2bf(a6 * w) | ((uint)f2bf(a7 * w) << 16);
    *reinterpret_cast<uint4*>(op + (size_t)node * 64 + ls * 8) = o;
}

} // namespace

extern "C" void kernel_launch(void* const* d_in, const int* in_sizes, int n_in,
                              void* d_out, int out_size, void* d_ws, size_t ws_size,
                              hipStream_t stream) {
    const float* x       = (const float*)d_in[0];
    const int*   ei1     = (const int*)d_in[1];
    const int*   ei2     = (const int*)d_in[2];
    const float* W_embed = (const float*)d_in[3];
    const float* b_embed = (const float*)d_in[4];
    const float* W0      = (const float*)d_in[5];
    const float* b0      = (const float*)d_in[6];
    const float* W1      = (const float*)d_in[7];
    const float* b1      = (const float*)d_in[8];
    const float* Wc      = (const float*)d_in[9];
    const float* bc      = (const float*)d_in[10];
    float* out = (float*)d_out;

    char* ws = (char*)d_ws;
    size_t off = 0;
    auto alloc = [&](size_t bytes) -> void* {
        void* p = ws + off;
        off += (bytes + 255) & ~(size_t)255;
        return p;
    };

    ushort* embB  = (ushort*)alloc((size_t)N * 192 * 2);  // bf16 [N][192]: r0 | r1 | r2
    ushort* n1b   = (ushort*)alloc((size_t)N * 64 * 2);
    ushort* n2b   = (ushort*)alloc((size_t)N * 64 * 2);
    int*    col   = (int*)alloc((size_t)NB * EBMAX * 4);
    uint*   ebuf  = (uint*)alloc((size_t)NB * EBMAX * 4);
    int*    rp    = (int*)alloc((size_t)M2 * 4);
    int*    rpe   = (int*)alloc((size_t)M2 * 4);
    float*  invd  = (float*)alloc((size_t)M2 * 4);
    int*    bcur  = (int*)alloc((NB + 1) * 4);
    ushort* wtE   = (ushort*)alloc(64 * 512 * 2);
    ushort* weff0 = (ushort*)alloc(64 * 192 * 2);
    ushort* weff1 = (ushort*)alloc(64 * 192 * 2);
    ushort* wct   = (ushort*)alloc(64 * 192 * 2);
    float*  bcp   = (float*)alloc(64 * 4);
    if (off > ws_size) return;

    const int* src1 = ei1, *dst1 = ei1 + E;
    const int* src2 = ei2, *dst2 = ei2 + E;

    const int GB  = (N + 127) / 128;         // 782
    const int GBE = N / 32;                  // 3125 (exact)
    const int PB  = (M2 * 8 + 255) / 256;    // 6250

    // ---- prep (bucket cursors to b*EBMAX + all weights) ----
    prep_all<<<128, 256, 0, stream>>>(W_embed, W0, W1, Wc, bc, bcur, wtE, weff0, weff1, wct, bcp);

    // ---- CSR build: scatter into fixed-capacity buckets, then per-bucket finalize ----
    bucket_scatter<<<AB, 256, 0, stream>>>(src1, dst1, src2, dst2, bcur, ebuf);
    csr_finalize<<<NB, 256, 0, stream>>>(ebuf, bcur, rp, rpe, invd, col);

    // ---- embed: r0 = relu(x @ W_embed + b) -> embB cols 0:64 (full-row staging) ----
    gemm_embed<<<GBE, 256, 0, stream>>>(x, wtE, b_embed, embB);

    // ---- layers ----
    for (int layer = 0; layer < 2; ++layer) {
        const ushort* rprev = embB + 64 * layer;
        spmm7<<<PB, 256, 0, stream>>>(rp, rpe, col, invd, embB, 64 * layer, n1b, n2b);
        const ushort* Wl = (layer == 0) ? weff0 : weff1;
        const float*  bl = (layer == 0) ? b0 : b1;
        gemm3<false><<<GB, 256, 0, stream>>>(rprev, 192, n1b, 64, n2b, 64, Wl, bl,
                                             embB + 64 * (layer + 1), 192, 64, 1);
    }

    // ---- classifier: logits = emb @ Wc + bc (f32 out, 47 cols) ----
    gemm3<true><<<GB, 256, 0, stream>>>(embB, 192, embB + 64, 192, embB + 128, 192, wct, bcp,
                                        out, NC, NC, 0);
}

// Round 9
// 218.173 us; speedup vs baseline: 1.4067x; 1.0248x over previous
//
#include <hip/hip_runtime.h>

namespace {

constexpr int N  = 100000;
constexpr int KD = 500;
constexpr int E  = 1200000;
constexpr int NC = 47;

constexpr int M2  = 2 * N;          // virtual nodes (graph1 | graph2)
constexpr int E2  = 2 * E;          // total edges
constexpr int NB  = 391;            // buckets of 512 virtual nodes (391*512 = 200192 >= M2)
constexpr int AB  = 586;            // scatter blocks (586*4096 >= E2)
constexpr int PREPB = 128;          // prep blocks fused ahead of scatter
constexpr int EBMAX = 8192;         // per-bucket edge cap (avg 6144, +26 sigma)
constexpr int LDE = 128;            // embB row stride (r0 | r1), 256 B rows

typedef __attribute__((ext_vector_type(8))) short short8;   // 8 bf16 = 4 VGPR
typedef __attribute__((ext_vector_type(4))) float f32x4;

__device__ __forceinline__ ushort f2bf(float f) {
    union { float f; uint u; } c; c.f = f;
    uint u = c.u + 0x7fffu + ((c.u >> 16) & 1);   // RNE
    return (ushort)(u >> 16);
}
__device__ __forceinline__ float bflo(uint v) { union { uint u; float f; } c; c.u = v << 16;        return c.f; }
__device__ __forceinline__ float bfhi(uint v) { union { uint u; float f; } c; c.u = v & 0xffff0000u; return c.f; }

// ---------------- fused: weight prep (blocks 0..127) || bucketed edge scatter (blocks 128..) ----------------
// cursor[] is zeroed by hipMemsetAsync before this kernel; scatter claims are bucket-local.

__global__ __launch_bounds__(256) void prep_scatter(
        const float* __restrict__ We, const float* __restrict__ W0,
        const float* __restrict__ W1, const float* __restrict__ Wc,
        const float* __restrict__ bc,
        const int* __restrict__ src1, const int* __restrict__ dst1,
        const int* __restrict__ src2, const int* __restrict__ dst2,
        int* __restrict__ cursor, uint* __restrict__ ebuf,
        ushort* __restrict__ wtE, ushort* __restrict__ wf0, ushort* __restrict__ wf1,
        ushort* __restrict__ wct, float* __restrict__ bcp) {
    __shared__ int h[NB];
    __shared__ int claim[NB];
    const int t = threadIdx.x;
    if (blockIdx.x < PREPB) {
        int i = blockIdx.x * 256 + t;
        if (i < 64 * 512) {
            int c = i >> 9, k = i & 511;
            wtE[i] = f2bf(k < KD ? We[k * 64 + c] : 0.f);
        }
        if (i < 64 * 192) {
            int c = i / 192, k = i % 192;
            float v0, v1;
            if (k < 64)       { v0 = W0[k * 64 + c] + W0[(128 + k) * 64 + c];
                                v1 = W1[k * 64 + c] + W1[(128 + k) * 64 + c]; }
            else if (k < 128) { v0 = W0[k * 64 + c]; v1 = W1[k * 64 + c]; }
            else              { v0 = W0[(k + 64) * 64 + c]; v1 = W1[(k + 64) * 64 + c]; }
            wf0[i] = f2bf(v0);
            wf1[i] = f2bf(v1);
            wct[i] = f2bf(c < NC ? Wc[k * NC + c] : 0.f);
        }
        if (i < 64) bcp[i] = (i < NC) ? bc[i] : 0.f;
    } else {
        const int blk = blockIdx.x - PREPB;
        int mb[16];
        uint mu[16];
        for (int b = t; b < NB; b += 256) h[b] = 0;
        __syncthreads();
        #pragma unroll
        for (int q = 0; q < 16; ++q) {
            int i = blk * 4096 + q * 256 + t;
            if (i < E2) {
                int g = i >= E;
                int idx = i - g * E;
                int s = g ? src2[idx] : src1[idx];
                int d = g ? dst2[idx] : dst1[idx];
                int v = g * N + s;
                mb[q] = v >> 9;
                mu[q] = ((uint)(v & 511) << 17) | (uint)d;
                atomicAdd(&h[mb[q]], 1);
            } else {
                mb[q] = -1;
                mu[q] = 0;
            }
        }
        __syncthreads();
        for (int b = t; b < NB; b += 256)
            claim[b] = h[b] ? atomicAdd(&cursor[b], h[b]) : 0;
        __syncthreads();
        for (int b = t; b < NB; b += 256) h[b] = 0;
        __syncthreads();
        #pragma unroll
        for (int q = 0; q < 16; ++q) {
            if (mb[q] >= 0) {
                int r = atomicAdd(&h[mb[q]], 1);
                ebuf[(size_t)mb[q] * EBMAX + claim[mb[q]] + r] = mu[q];
            }
        }
    }
}

// one block per bucket: build 512-node CSR window in LDS, write rp/rpe/invd/col
__global__ __launch_bounds__(256) void csr_finalize(const uint* __restrict__ ebuf, const int* __restrict__ cursor,
                                                    int* __restrict__ rp, int* __restrict__ rpe,
                                                    float* __restrict__ invd, int* __restrict__ col) {
    __shared__ uint eb[EBMAX];
    __shared__ int h[512];
    __shared__ int ex[512];
    __shared__ int ps[256];
    int bid = blockIdx.x;
    int t = threadIdx.x;
    int b0 = bid * EBMAX;
    int cnt = cursor[bid];              // bucket-local count
    if (cnt > EBMAX) cnt = EBMAX;
    if (cnt < 0) cnt = 0;
    h[t] = 0; h[t + 256] = 0;
    for (int j = t; j < cnt; j += 256) eb[j] = ebuf[b0 + j];
    __syncthreads();
    for (int j = t; j < cnt; j += 256) atomicAdd(&h[eb[j] >> 17], 1);
    __syncthreads();
    int pv = h[2 * t] + h[2 * t + 1];
    ps[t] = pv;
    __syncthreads();
    for (int off = 1; off < 256; off <<= 1) {
        int xv = (t >= off) ? ps[t - off] : 0;
        __syncthreads();
        ps[t] += xv;
        __syncthreads();
    }
    int e2 = ps[t] - pv;
    ex[2 * t] = e2;
    ex[2 * t + 1] = e2 + h[2 * t];
    __syncthreads();
    #pragma unroll
    for (int q = 0; q < 2; ++q) {
        int k = q * 256 + t;
        int n = bid * 512 + k;
        if (n < M2) {
            int st = b0 + ex[k];
            int dv = h[k];
            rp[n]  = st;
            rpe[n] = st + dv;
            invd[n] = 1.0f / (float)(dv > 1 ? dv : 1);
        }
    }
    __syncthreads();
    for (int j = t; j < cnt; j += 256) {
        uint u = eb[j];
        int ls = u >> 17;
        int r = atomicAdd(&ex[ls], 1);
        col[b0 + r] = (int)(u & 0x1FFFFu) * 256;   // byte offset of node row in embB (128 ushort = 256 B)
    }
}

// ---------------- MFMA GEMM core ----------------

__device__ __forceinline__ void stageB(const ushort* __restrict__ Wt, int ldw, int k0, short* Bs) {
    const int tid = threadIdx.x;
    #pragma unroll
    for (int i = 0; i < 2; ++i) {
        int idx = tid + i * 256;
        int c = idx >> 3, qc = (idx & 7) * 8;
        uint4 v = *reinterpret_cast<const uint4*>(Wt + (size_t)c * ldw + k0 + qc);
        *reinterpret_cast<uint4*>(Bs + (((c << 6) + qc) ^ ((c & 7) << 3))) = v;
    }
}

__device__ __forceinline__ void mma64(const short* As, const short* Bs, f32x4 acc[2][4]) {
    const int lane = threadIdx.x & 63;
    const int wrow = (threadIdx.x >> 6) * 32;
    const int llo = lane & 15, lhi = lane >> 4;
    #pragma unroll
    for (int kf = 0; kf < 2; ++kf) {
        const int kb = kf * 32 + lhi * 8;
        short8 a[2], b[4];
        #pragma unroll
        for (int m = 0; m < 2; ++m) {
            int r = wrow + m * 16 + llo;
            a[m] = *reinterpret_cast<const short8*>(As + (((r << 6) + kb) ^ ((r & 7) << 3)));
        }
        #pragma unroll
        for (int n = 0; n < 4; ++n) {
            int c = n * 16 + llo;
            b[n] = *reinterpret_cast<const short8*>(Bs + (((c << 6) + kb) ^ ((c & 7) << 3)));
        }
        #pragma unroll
        for (int m = 0; m < 2; ++m)
            #pragma unroll
            for (int n = 0; n < 4; ++n)
                acc[m][n] = __builtin_amdgcn_mfma_f32_16x16x32_bf16(a[m], b[n], acc[m][n], 0, 0, 0);
    }
}

template<bool OUTF32>
__device__ __forceinline__ void epilogue(f32x4 acc[2][4], const float* __restrict__ bias,
                                         void* out, int ldo, int ocols, int relu, int rbase) {
    const int lane = threadIdx.x & 63;
    const int wrow = (threadIdx.x >> 6) * 32;
    #pragma unroll
    for (int m = 0; m < 2; ++m) {
        #pragma unroll
        for (int r = 0; r < 4; ++r) {
            int orow = rbase + wrow + m * 16 + (lane >> 4) * 4 + r;
            if (orow >= N) continue;
            #pragma unroll
            for (int n = 0; n < 4; ++n) {
                int c = n * 16 + (lane & 15);
                float v = acc[m][n][r] + bias[c];
                if (relu) v = fmaxf(v, 0.f);
                if (OUTF32) {
                    if (c < ocols) ((float*)out)[(size_t)orow * ldo + c] = v;
                } else {
                    ((ushort*)out)[(size_t)orow * ldo + c] = f2bf(v);
                }
            }
        }
    }
}

// ---------------- embed GEMM, full-row staging (round-8 form, out stride 128) ----------------

__global__ __launch_bounds__(256) void gemm_embed(const float* __restrict__ x,
                                                  const ushort* __restrict__ WtE,
                                                  const float* __restrict__ bias,
                                                  ushort* __restrict__ out) {
    __shared__ short As[32 * 512];
    __shared__ short Bs[64 * 64];
    const int tid = threadIdx.x;
    const int rbase = blockIdx.x * 32;
    const int r = tid >> 3;          // 0..31
    const int j = tid & 7;
    const int swz = (r & 7) << 3;

    const float* xrow = x + (size_t)(rbase + r) * KD;
    float4 pv[16];
    #pragma unroll
    for (int i = 0; i < 16; ++i) {
        int qc = i * 32 + j * 4;
        float4 v = {0.f, 0.f, 0.f, 0.f};
        if (qc < KD) v = *reinterpret_cast<const float4*>(xrow + qc);
        pv[i] = v;
    }
    #pragma unroll
    for (int i = 0; i < 16; ++i) {
        int qc = i * 32 + j * 4;
        uint2 p;
        p.x = (uint)f2bf(pv[i].x) | ((uint)f2bf(pv[i].y) << 16);
        p.y = (uint)f2bf(pv[i].z) | ((uint)f2bf(pv[i].w) << 16);
        *reinterpret_cast<uint2*>(As + ((r << 9) + (qc ^ swz))) = p;
    }

    const int lane = tid & 63;
    const int w = tid >> 6;
    const int llo = lane & 15, lhi = lane >> 4;
    f32x4 acc[2] = {};
    for (int k0 = 0; k0 < 512; k0 += 64) {
        __syncthreads();
        stageB(WtE, 512, k0, Bs);
        __syncthreads();
        #pragma unroll
        for (int kf = 0; kf < 2; ++kf) {
            const int kbl = kf * 32 + lhi * 8;
            const int kab = k0 + kbl;
            short8 a[2], b;
            #pragma unroll
            for (int m = 0; m < 2; ++m) {
                int ar = m * 16 + llo;
                a[m] = *reinterpret_cast<const short8*>(As + ((ar << 9) + (kab ^ ((ar & 7) << 3))));
            }
            {
                int c = w * 16 + llo;
                b = *reinterpret_cast<const short8*>(Bs + (((c << 6) + kbl) ^ ((c & 7) << 3)));
            }
            #pragma unroll
            for (int m = 0; m < 2; ++m)
                acc[m] = __builtin_amdgcn_mfma_f32_16x16x32_bf16(a[m], b, acc[m], 0, 0, 0);
        }
    }

    #pragma unroll
    for (int m = 0; m < 2; ++m) {
        #pragma unroll
        for (int rr = 0; rr < 4; ++rr) {
            int orow = rbase + m * 16 + lhi * 4 + rr;
            int c = w * 16 + llo;
            float v = acc[m][rr] + bias[c];
            v = fmaxf(v, 0.f);
            out[(size_t)orow * LDE + c] = f2bf(v);
        }
    }
}

// ---------------- layer-0 GEMM (3 segments, bf16 out to embB r1) ----------------

__global__ __launch_bounds__(256) void gemm3(const ushort* __restrict__ a0, int lda0,
                                             const ushort* __restrict__ a1, int lda1,
                                             const ushort* __restrict__ a2, int lda2,
                                             const ushort* __restrict__ Wt,
                                             const float* __restrict__ bias,
                                             ushort* __restrict__ out, int ldo) {
    __shared__ short As[128 * 64];
    __shared__ short Bs[64 * 64];
    const int tid = threadIdx.x;
    const int rbase = blockIdx.x * 128;
    f32x4 acc[2][4] = {};
    const ushort* aseg[3] = {a0, a1, a2};
    const int ldas[3] = {lda0, lda1, lda2};
    #pragma unroll
    for (int seg = 0; seg < 3; ++seg) {
        const ushort* A = aseg[seg];
        const int lda = ldas[seg];
        __syncthreads();
        #pragma unroll
        for (int i = 0; i < 4; ++i) {
            int idx = tid + i * 256;
            int r = idx >> 3, qc = (idx & 7) * 8;
            int grow = rbase + r;
            uint4 v = {0u, 0u, 0u, 0u};
            if (grow < N) v = *reinterpret_cast<const uint4*>(A + (size_t)grow * lda + qc);
            *reinterpret_cast<uint4*>(As + (((r << 6) + qc) ^ ((r & 7) << 3))) = v;
        }
        stageB(Wt, 192, seg * 64, Bs);
        __syncthreads();
        mma64(As, Bs, acc);
    }
    epilogue<false>(acc, bias, out, ldo, 64, 1, rbase);
}

// ---------------- fused layer-1 + classifier: r2 stays on-chip ----------------
// acc1 = r2 pre-activation (weff1 over r1|n1|n2); acc2 = logits (wct over r1, r2, r0).
// r2 is written (bias+relu+f2bf) into the As LDS tile -> identical bf16 values to the old
// global round-trip, consumed directly by the cls MFMA. r2 never touches global memory.

__global__ __launch_bounds__(256) void gemm_l1cls(const ushort* __restrict__ embB,
                                                  const ushort* __restrict__ n1b,
                                                  const ushort* __restrict__ n2b,
                                                  const ushort* __restrict__ W1t,
                                                  const float* __restrict__ b1,
                                                  const ushort* __restrict__ Wct,
                                                  const float* __restrict__ bcp,
                                                  float* __restrict__ out) {
    __shared__ short As[128 * 64];
    __shared__ short Bs1[64 * 64];
    __shared__ short Bs2[64 * 64];
    const int tid = threadIdx.x;
    const int rbase = blockIdx.x * 128;
    f32x4 acc1[2][4] = {};
    f32x4 acc2[2][4] = {};

    auto stageA = [&](const ushort* A, int lda) {
        #pragma unroll
        for (int i = 0; i < 4; ++i) {
            int idx = tid + i * 256;
            int r = idx >> 3, qc = (idx & 7) * 8;
            int grow = rbase + r;
            uint4 v = {0u, 0u, 0u, 0u};
            if (grow < N) v = *reinterpret_cast<const uint4*>(A + (size_t)grow * lda + qc);
            *reinterpret_cast<uint4*>(As + (((r << 6) + qc) ^ ((r & 7) << 3))) = v;
        }
    };

    // r1 tile shared by layer-1 seg0 and cls seg1
    stageA(embB + 64, LDE);
    stageB(W1t, 192, 0, Bs1);
    stageB(Wct, 192, 64, Bs2);
    __syncthreads();
    mma64(As, Bs1, acc1);
    mma64(As, Bs2, acc2);
    __syncthreads();

    stageA(n1b, 64);
    stageB(W1t, 192, 64, Bs1);
    __syncthreads();
    mma64(As, Bs1, acc1);
    __syncthreads();

    stageA(n2b, 64);
    stageB(W1t, 192, 128, Bs1);
    __syncthreads();
    mma64(As, Bs1, acc1);
    __syncthreads();

    // r2 = relu(acc1 + b1) -> bf16 -> As (swizzled), then cls seg2
    {
        const int lane = tid & 63;
        const int wrow = (tid >> 6) * 32;
        #pragma unroll
        for (int m = 0; m < 2; ++m) {
            #pragma unroll
            for (int r = 0; r < 4; ++r) {
                int row = wrow + m * 16 + (lane >> 4) * 4 + r;
                #pragma unroll
                for (int n = 0; n < 4; ++n) {
                    int c = n * 16 + (lane & 15);
                    float v = fmaxf(acc1[m][n][r] + b1[c], 0.f);
                    As[(((row << 6) + c) ^ ((row & 7) << 3))] = (short)f2bf(v);
                }
            }
        }
    }
    stageB(Wct, 192, 128, Bs1);
    __syncthreads();
    mma64(As, Bs1, acc2);
    __syncthreads();

    // cls seg0: r0
    stageA(embB, LDE);
    stageB(Wct, 192, 0, Bs1);
    __syncthreads();
    mma64(As, Bs1, acc2);

    epilogue<true>(acc2, bcp, out, NC, NC, 0, rbase);
}

// ---------------- SPMM: 8 lanes per node, uint4 row reads (1 line per edge), 8-deep MLP unroll ----------------

__global__ __launch_bounds__(256) void spmm7(const int* __restrict__ rp, const int* __restrict__ rpe,
                                             const int* __restrict__ col,
                                             const float* __restrict__ invd,
                                             const ushort* __restrict__ table, int colOff,
                                             ushort* __restrict__ n1b, ushort* __restrict__ n2b) {
    int gid = (blockIdx.x * 256 + threadIdx.x) >> 3;   // virtual node
    int ls = threadIdx.x & 7;
    if (gid >= M2) return;
    const char* hb = (const char*)(table + colOff) + ls * 16;
    float w = invd[gid];
    int s = rp[gid], e = rpe[gid];
    int e1 = e - 1;
    float a0=0.f,a1=0.f,a2=0.f,a3=0.f,a4=0.f,a5=0.f,a6=0.f,a7=0.f;
    for (int j = s; j < e; j += 8) {
        int off[8];
        float wv[8];
        #pragma unroll
        for (int u = 0; u < 8; ++u) {
            int jj = j + u;
            int cidx = jj < e ? jj : e1;
            off[u] = col[cidx];
            wv[u] = jj < e ? 1.f : 0.f;
        }
        uint4 v[8];
        #pragma unroll
        for (int u = 0; u < 8; ++u) v[u] = *reinterpret_cast<const uint4*>(hb + off[u]);
        #pragma unroll
        for (int u = 0; u < 8; ++u) {
            a0 = fmaf(wv[u], bflo(v[u].x), a0); a1 = fmaf(wv[u], bfhi(v[u].x), a1);
            a2 = fmaf(wv[u], bflo(v[u].y), a2); a3 = fmaf(wv[u], bfhi(v[u].y), a3);
            a4 = fmaf(wv[u], bflo(v[u].z), a4); a5 = fmaf(wv[u], bfhi(v[u].z), a5);
            a6 = fmaf(wv[u], bflo(v[u].w), a6); a7 = fmaf(wv[u], bfhi(v[u].w), a7);
        }
    }
    int g = gid >= N;
    int node = gid - g * N;
    ushort* op = g ? n2b : n1b;
    uint4 o;
    o.x = (uint)f2bf(a0 * w) | ((uint)f2bf(a1 * w) << 16);
    o.y = (uint)f2bf(a2 * w) | ((uint)f2bf(a3 * w) << 16);
    o.z = (uint)f2bf(a4 * w) | ((uint)f2bf(a5 * w) << 16);
    o.w = (uint)f2bf(a6 * w) | ((uint)f2bf(a7 * w) << 16);
    *reinterpret_cast<uint4*>(op + (size_t)node * 64 + ls * 8) = o;
}

} // namespace

extern "C" void kernel_launch(void* const* d_in, const int* in_sizes, int n_in,
                              void* d_out, int out_size, void* d_ws, size_t ws_size,
                              hipStream_t stream) {
    const float* x       = (const float*)d_in[0];
    const int*   ei1     = (const int*)d_in[1];
    const int*   ei2     = (const int*)d_in[2];
    const float* W_embed = (const float*)d_in[3];
    const float* b_embed = (const float*)d_in[4];
    const float* W0      = (const float*)d_in[5];
    const float* b0      = (const float*)d_in[6];
    const float* W1      = (const float*)d_in[7];
    const float* b1      = (const float*)d_in[8];
    const float* Wc      = (const float*)d_in[9];
    const float* bc      = (const float*)d_in[10];
    float* out = (float*)d_out;

    char* ws = (char*)d_ws;
    size_t off = 0;
    auto alloc = [&](size_t bytes) -> void* {
        void* p = ws + off;
        off += (bytes + 255) & ~(size_t)255;
        return p;
    };

    ushort* embB  = (ushort*)alloc((size_t)N * LDE * 2);  // bf16 [N][128]: r0 | r1
    ushort* n1b   = (ushort*)alloc((size_t)N * 64 * 2);
    ushort* n2b   = (ushort*)alloc((size_t)N * 64 * 2);
    int*    col   = (int*)alloc((size_t)NB * EBMAX * 4);
    uint*   ebuf  = (uint*)alloc((size_t)NB * EBMAX * 4);
    int*    rp    = (int*)alloc((size_t)M2 * 4);
    int*    rpe   = (int*)alloc((size_t)M2 * 4);
    float*  invd  = (float*)alloc((size_t)M2 * 4);
    int*    bcur  = (int*)alloc((NB + 1) * 4);
    ushort* wtE   = (ushort*)alloc(64 * 512 * 2);
    ushort* weff0 = (ushort*)alloc(64 * 192 * 2);
    ushort* weff1 = (ushort*)alloc(64 * 192 * 2);
    ushort* wct   = (ushort*)alloc(64 * 192 * 2);
    float*  bcp   = (float*)alloc(64 * 4);
    if (off > ws_size) return;

    const int* src1 = ei1, *dst1 = ei1 + E;
    const int* src2 = ei2, *dst2 = ei2 + E;

    const int GB  = (N + 127) / 128;         // 782
    const int GBE = N / 32;                  // 3125 (exact)
    const int PB  = (M2 * 8 + 255) / 256;    // 6250

    // ---- zero bucket cursors (graph-capture-safe async memset) ----
    hipMemsetAsync(bcur, 0, NB * sizeof(int), stream);

    // ---- fused: weight prep || edge scatter ----
    prep_scatter<<<PREPB + AB, 256, 0, stream>>>(W_embed, W0, W1, Wc, bc,
                                                 src1, dst1, src2, dst2, bcur, ebuf,
                                                 wtE, weff0, weff1, wct, bcp);

    // ---- CSR finalize ----
    csr_finalize<<<NB, 256, 0, stream>>>(ebuf, bcur, rp, rpe, invd, col);

    // ---- embed: r0 = relu(x @ W_embed + b) -> embB cols 0:64 ----
    gemm_embed<<<GBE, 256, 0, stream>>>(x, wtE, b_embed, embB);

    // ---- layer 0: spmm over r0, then r1 = relu([r0|n1|n2] @ weff0 + b0) ----
    spmm7<<<PB, 256, 0, stream>>>(rp, rpe, col, invd, embB, 0, n1b, n2b);
    gemm3<<<GB, 256, 0, stream>>>(embB, LDE, n1b, 64, n2b, 64, weff0, b0, embB + 64, LDE);

    // ---- layer 1 spmm over r1, then fused layer-1 GEMM + classifier ----
    spmm7<<<PB, 256, 0, stream>>>(rp, rpe, col, invd, embB, 64, n1b, n2b);
    gemm_l1cls<<<GB, 256, 0, stream>>>(embB, n1b, n2b, weff1, b1, wct, bcp, out);
}